// Round 17
// baseline (448.604 us; speedup 1.0000x reference)
//
#include <hip/hip_runtime.h>

#define PTS 32768
#define BP (PTS*256)             // elements per batch of x / v / out
#define QKSZ (16*PTS)
#define Q_OFF ((size_t)0)
#define K_OFF ((size_t)4194304)
#define P_OFF ((size_t)8388608)   // 64 ch * 2048 partials
#define ATT_OFF ((size_t)67108864)
#define WS_V_USH ((size_t)0)
#define WS_ATT_USH ((size_t)67108864)
#define WS_W_USH ((size_t)67633152)   // 9216 x 16B pre-swizzled W image (288 rows x 32 chunks)
#define WS_NEED ((size_t)135450624)

typedef __attribute__((ext_vector_type(8))) short short8;
typedef __attribute__((ext_vector_type(4))) float f32x4;
typedef __attribute__((ext_vector_type(4))) unsigned short ush4;

__device__ __forceinline__ unsigned short f2bf(float f){
  unsigned u = __float_as_uint(f);
  u += 0x7FFFu + ((u>>16)&1u);
  return (unsigned short)(u>>16);
}

__device__ __forceinline__ void bar_lgkm(){
  asm volatile("s_waitcnt lgkmcnt(0)" ::: "memory");
  __builtin_amdgcn_s_barrier();
}

// ---------------- K0: pre-swizzled bf16 W image.
// wimg2[r*256 + q*8 .. +8) = bf16(W[r][ ((q ^ (r&31))*8) .. +8 ])
// rows 0-255 = Wv, 256-271 = Wq, 272-287 = Wk.  9216 16B-chunks total.
__global__ void __launch_bounds__(256) k_wprep2(const float* __restrict__ Wv,
    const float* __restrict__ Wq, const float* __restrict__ Wk,
    unsigned short* __restrict__ wimg2){
  int t = blockIdx.x*256 + threadIdx.x;
  if (t >= 9216) return;
  int r = t>>5, qp = t&31;
  const float* src = (r < 256) ? (Wv + (size_t)r*256)
                    : (r < 272) ? (Wq + (size_t)(r-256)*256)
                                : (Wk + (size_t)(r-272)*256);
  int c0 = (qp ^ (r&31))*8;
  short8 h;
  #pragma unroll
  for (int j=0;j<8;j++) h[j] = (short)f2bf(src[c0+j]);
  *(short8*)&wimg2[(size_t)t*8] = h;
}

// ---------------- FAST K-A: barrier-free fused v/q/k GEMM (round-11 base + depth-2 x prefetch).
// W fully resident in LDS (144KB, loaded once). Each wave independently computes
// 32p x (256 v-m + 32 qk) tiles: x A-frags direct global->reg (DOUBLE-buffered,
// 2-kk-deep prefetch to cover L3/HBM latency), W B-frags from LDS.
__global__ void __launch_bounds__(512, 2) k_fused4(const float* __restrict__ x,
    const float* __restrict__ bv, const float* __restrict__ bq, const float* __restrict__ bk,
    const unsigned short* __restrict__ wimg2,
    unsigned short* __restrict__ vws, float* __restrict__ scr){
  __shared__ __align__(16) unsigned short Wl[73728];  // 288 rows x 256 ush, chunk-swizzled (144KB)
  __shared__ __align__(16) float qkT[2048];           // 8 waves x 256 f32 private slices (8KB)
  int t = threadIdx.x;
  int w = t>>6, l = t&63;
  int l15 = l&15, l4 = l>>4;

  { // stage W: linear 16B copy, 18 chunks/thread
    const short8* src = (const short8*)wimg2;
    short8* dst = (short8*)Wl;
    #pragma unroll
    for (int i=0;i<18;i++) dst[t + 512*i] = src[t + 512*i];
  }
  __syncthreads();                 // the ONLY block-wide barrier

  float* qslice = qkT + w*256;
  float bvv[16];
  #pragma unroll
  for (int mb=0;mb<16;mb++) bvv[mb] = bv[mb*16 + l15];
  float bqv = bq[l15], bkv = bk[l15];

  int gw = blockIdx.x*8 + w;       // 0..2047
  for (int it=0; it<4; ++it){
    int tau = gw + 2048*it;        // 0..8191
    int b = tau>>10;
    int p0 = (tau&1023)*32;
    const float* xb = x + (size_t)b*BP + p0 + l15;
    f32x4 acc[2][16] = {};
    f32x4 acce[4] = {};

    // prologue: prefetch kk=0 and kk=1 x values (depth-2 double buffer)
    float xv[2][2][8];             // [buf = kk&1][ps][j]
    #pragma unroll
    for (int kk0=0; kk0<2; kk0++)
      #pragma unroll
      for (int ps=0; ps<2; ps++)
        #pragma unroll
        for (int j=0;j<8;j++)
          xv[kk0][ps][j] = xb[(size_t)(kk0*32 + l4*8 + j)*PTS + ps*16];

    #pragma unroll
    for (int kk=0; kk<8; kk++){
      const int cur = kk&1;
      short8 af[2];
      #pragma unroll
      for (int ps=0; ps<2; ps++){
        short8 h;
        #pragma unroll
        for (int j=0;j<8;j++) h[j] = (short)f2bf(xv[cur][ps][j]);
        af[ps] = h;
      }
      if (kk < 6){                 // refill this buffer for kk+2 (2-deep in flight)
        #pragma unroll
        for (int ps=0; ps<2; ps++)
          #pragma unroll
          for (int j=0;j<8;j++)
            xv[cur][ps][j] = xb[(size_t)((kk+2)*32 + l4*8 + j)*PTS + ps*16];
      }
      #pragma unroll
      for (int mb=0; mb<16; mb++){
        int m = mb*16 + l15;
        int phys = (kk*4 + l4) ^ (m&31);
        short8 bf = *(const short8*)&Wl[m*256 + phys*8];
        acc[0][mb] = __builtin_amdgcn_mfma_f32_16x16x32_bf16(af[0], bf, acc[0][mb], 0, 0, 0);
        acc[1][mb] = __builtin_amdgcn_mfma_f32_16x16x32_bf16(af[1], bf, acc[1][mb], 0, 0, 0);
      }
      #pragma unroll
      for (int qs=0; qs<2; qs++){
        int m = 256 + qs*16 + l15;
        int phys = (kk*4 + l4) ^ (m&31);
        short8 bf = *(const short8*)&Wl[m*256 + phys*8];
        acce[qs*2+0] = __builtin_amdgcn_mfma_f32_16x16x32_bf16(af[0], bf, acce[qs*2+0], 0, 0, 0);
        acce[qs*2+1] = __builtin_amdgcn_mfma_f32_16x16x32_bf16(af[1], bf, acce[qs*2+1], 0, 0, 0);
      }
    }

    // v store: vws[b][p][m] (flat == what k_out5 reads). Per instr: 4 p-rows x 32B;
    // adjacent mb instrs complete each 64B sector.
    unsigned short* vb = vws + (size_t)b*BP;
    #pragma unroll
    for (int ps=0; ps<2; ps++){
      #pragma unroll
      for (int j=0;j<4;j++){
        int p = p0 + ps*16 + l4*4 + j;
        unsigned short* row = vb + (size_t)p*256 + l15;
        #pragma unroll
        for (int mb=0; mb<16; mb++)
          row[mb*16] = f2bf(acc[ps][mb][j] + bvv[mb]);
      }
    }
    // q/k: transpose 16p x 16f through private LDS slice, store [f][p] full lines
    #pragma unroll
    for (int ps=0; ps<2; ps++){
      #pragma unroll
      for (int qs=0; qs<2; qs++){
        float bias = qs ? bkv : bqv;
        #pragma unroll
        for (int j=0;j<4;j++){
          int pl = l4*4 + j;
          qslice[pl*16 + (l15 ^ pl)] = acce[qs*2+ps][j] + bias;
        }
        float* qdst = scr + (qs ? K_OFF : Q_OFF) + (size_t)b*QKSZ;
        #pragma unroll
        for (int r=0;r<4;r++){
          int f = r*4 + l4;
          float v = qslice[l15*16 + (f ^ l15)];
          qdst[(size_t)f*PTS + p0 + ps*16 + l15] = v;
        }
      }
    }
  }
}

// ---------------- K2: energy partials, q/k read exactly once.
__global__ void __launch_bounds__(256) k_energy2(float* __restrict__ scr){
  __shared__ float ql[16][512];
  __shared__ float red[256][17];
  int t = threadIdx.x;
  int ch = blockIdx.x, b = blockIdx.y;
  int pbase = ch*512;
  const float* qb = scr + Q_OFF + (size_t)b*QKSZ;
  #pragma unroll
  for (int i=0;i<8;i++){
    int fid = t + 256*i;
    int f = fid>>7, p4 = fid&127;
    float4 v = *(const float4*)(qb + (size_t)f*PTS + pbase + p4*4);
    *(float4*)&ql[f][p4*4] = v;
  }
  __syncthreads();
  const float* kb = scr + K_OFF + (size_t)b*QKSZ + (size_t)ch*8192;
  float acc[16];
  #pragma unroll
  for (int f=0;f<16;f++) acc[f]=0.f;
  for (int i=0;i<32;i++){
    float kv = kb[i*256 + t];
    int p = i*16 + (t>>4);
    #pragma unroll
    for (int f=0;f<16;f++) acc[f] += kv*ql[f][p];
  }
  #pragma unroll
  for (int f=0;f<16;f++) red[t][f] = acc[f];
  __syncthreads();
  int f = t>>4, g = t&15;
  float s = 0.f;
  #pragma unroll
  for (int k=0;k<16;k++) s += red[g + 16*k][f];
  scr[P_OFF + (size_t)ch*2048 + (size_t)b*256 + t] = s;
}

// ---------------- K3: fused reduce + softmax, r-chunked over 64 blocks.
__global__ void __launch_bounds__(256) k_softmax2(float* __restrict__ scr,
    const float* __restrict__ Wup, const float* __restrict__ bup,
    unsigned short* __restrict__ attT){
  __shared__ float el[256];
  int rc = blockIdx.x, b = blockIdx.y, t = threadIdx.x;
  {
    float s = 0.f;
    for (int ch=0; ch<64; ch++) s += scr[P_OFF + (size_t)ch*2048 + (size_t)b*256 + t];
    el[t] = s;
  }
  __syncthreads();
  int ec = t>>4, kw = t&15;
  float bupv = bup[0];
  bool sp = (kw < 3);
  float w0=0.f,w1=0.f,w2=0.f;
  if (sp){ w0 = Wup[kw]; w1 = Wup[3+kw]; w2 = Wup[6+kw]; }
  float m = bupv;
  float sum;
  if (sp){
    #pragma unroll
    for (int rh=0; rh<16; rh++){
      float e = el[rh*16+ec];
      m = fmaxf(m, fmaxf(fmaxf(w0*e, w1*e), w2*e) + bupv);
    }
    sum = 208.f*__expf(bupv - m);
    for (int rh=0; rh<16; rh++){
      float e = el[rh*16+ec];
      sum += __expf(bupv + w0*e - m) + __expf(bupv + w1*e - m) + __expf(bupv + w2*e - m);
    }
  } else {
    sum = 256.f;
  }
  float inv = 1.f/sum;
  float* attp = scr + ATT_OFF + (size_t)b*65536;
  unsigned short* attTp = attT ? (attT + (size_t)b*65536 + (size_t)t*256) : nullptr;
  int r0 = rc*32;
  for (int r=r0; r<r0+32; r++){
    int kh = r&15;
    float v;
    if (sp && kh < 3){
      float e = el[(r>>4)*16 + ec];
      float w = (kh==0)? w0 : ((kh==1)? w1 : w2);
      v = __expf(bupv + w*e - m)*inv;
    } else {
      v = __expf(bupv - m)*inv;
    }
    attp[(size_t)r*256 + t] = v;
    if (attTp) attTp[r] = f2bf(v);
  }
}

// ---------------- FAST K4b: register-resident attT B-frags; V tile prefetched to regs.
__global__ void __launch_bounds__(256, 2) k_out5(const float* __restrict__ x,
    const float* __restrict__ gma,
    const unsigned short* __restrict__ vws,
    const unsigned short* __restrict__ attT,
    float* __restrict__ outb){
  __shared__ __align__(16) unsigned short Vt[32*256];
  __shared__ __align__(16) float Ot[32*260];
  int t = threadIdx.x;
  int b = blockIdx.y;
  int wc = t>>6, l = t&63;
  int l15 = l&15, l4 = l>>4;
  float gm = gma[0];
  const unsigned short* tb = attT + (size_t)b*65536;
  short8 bfv[4][8];
  #pragma unroll
  for (int ni=0;ni<4;ni++){
    int g = wc*64 + ni*16 + l15;
    #pragma unroll
    for (int ks=0;ks<8;ks++)
      bfv[ni][ks] = *(const short8*)(tb + (size_t)g*256 + ks*32 + l4*8);
  }
  short8 vreg[4];
  {
    int p0 = blockIdx.x*32;
    const unsigned short* vsrc = vws + (size_t)b*BP + (size_t)p0*256;
    #pragma unroll
    for (int i=0;i<4;i++) vreg[i] = *(const short8*)(vsrc + (size_t)(i*256+t)*8);
  }
  for (int it=0; it<8; ++it){
    int p0 = (blockIdx.x + 128*it)*32;
    #pragma unroll
    for (int i=0;i<4;i++){
      int idx = i*256 + t;
      int row = idx>>5, chunk = idx&31;
      *(short8*)&Vt[row*256 + ((chunk ^ row)&31)*8] = vreg[i];
    }
    if (it < 7){
      int pn = (blockIdx.x + 128*(it+1))*32;
      const unsigned short* vsrc = vws + (size_t)b*BP + (size_t)pn*256;
      #pragma unroll
      for (int i=0;i<4;i++) vreg[i] = *(const short8*)(vsrc + (size_t)(i*256+t)*8);
    }
    bar_lgkm();
    #pragma unroll
    for (int mi=0;mi<2;mi++){
      int row = mi*16 + l15;
      short8 af[8];
      #pragma unroll
      for (int ks=0;ks<8;ks++){
        int chunk = ks*4 + l4;
        af[ks] = *(const short8*)&Vt[row*256 + ((chunk ^ row)&31)*8];
      }
      #pragma unroll
      for (int ni=0;ni<4;ni++){
        f32x4 acc = {};
        #pragma unroll
        for (int ks=0;ks<8;ks++)
          acc = __builtin_amdgcn_mfma_f32_16x16x32_bf16(af[ks], bfv[ni][ks], acc, 0, 0, 0);
        int gl = wc*64 + ni*16 + l15;
        #pragma unroll
        for (int j=0;j<4;j++)
          Ot[(mi*16 + l4*4 + j)*260 + gl] = acc[j];
      }
    }
    bar_lgkm();
    size_t base = (size_t)b*BP + (size_t)p0*256;
    const float* xb = x + base;
    float* ob = outb + base;
    #pragma unroll
    for (int i=0;i<8;i++){
      int f4 = i*256 + t;
      int row = f4>>6, col = (f4&63)*4;
      float4 a = *(const float4*)&Ot[row*260 + col];
      float4 xv = *(const float4*)(xb + (size_t)f4*4);
      float4 r;
      r.x = gm*a.x + xv.x; r.y = gm*a.y + xv.y;
      r.z = gm*a.z + xv.z; r.w = gm*a.w + xv.w;
      *(float4*)(ob + (size_t)f4*4) = r;
    }
  }
}

// ================= FALLBACK (round-1 pipeline, f32 v in-place in d_out) =================
__global__ void __launch_bounds__(256) k_qk(const float* __restrict__ x,
    const float* __restrict__ Wq, const float* __restrict__ bq,
    const float* __restrict__ Wk, const float* __restrict__ bk,
    float* __restrict__ scr){
  __shared__ float wlds[256][36];
  int t = threadIdx.x;
  int b = blockIdx.y;
  int p = blockIdx.x*256 + t;
  for (int idx = t; idx < 4096; idx += 256){
    int o = idx>>8, c = idx&255;
    wlds[c][o]    = Wq[idx];
    wlds[c][16+o] = Wk[idx];
  }
  __syncthreads();
  const float* xb = x + (size_t)b*BP;
  float qa[16], ka[16];
  #pragma unroll
  for (int o=0;o<16;o++){ qa[o]=0.f; ka[o]=0.f; }
  for (int c=0;c<256;c++){
    float xv = xb[(size_t)c*PTS + p];
    const float4* wrow = (const float4*)(&wlds[c][0]);
    #pragma unroll
    for (int i=0;i<4;i++){
      float4 wq = wrow[i], wk = wrow[4+i];
      qa[4*i+0] += wq.x*xv; qa[4*i+1] += wq.y*xv; qa[4*i+2] += wq.z*xv; qa[4*i+3] += wq.w*xv;
      ka[4*i+0] += wk.x*xv; ka[4*i+1] += wk.y*xv; ka[4*i+2] += wk.z*xv; ka[4*i+3] += wk.w*xv;
    }
  }
  size_t qb = (size_t)b*QKSZ;
  #pragma unroll
  for (int o=0;o<16;o++){
    scr[Q_OFF + qb + (size_t)o*PTS + p] = qa[o] + bq[o];
    scr[K_OFF + qb + (size_t)o*PTS + p] = ka[o] + bk[o];
  }
}

__global__ void __launch_bounds__(256) k_vgemm(const float* __restrict__ x,
    const float* __restrict__ Wv, const float* __restrict__ bv,
    float* __restrict__ outb){
  __shared__ short At[128][40];
  __shared__ short Bt[128][40];
  int t = threadIdx.x;
  int mt = blockIdx.x, nt = blockIdx.y, b = blockIdx.z;
  const float* xb = x + (size_t)b*BP + (size_t)nt*128;
  const float* Av = Wv + (size_t)mt*128*256;
  int w = t>>6, l = t&63;
  int wr = w>>1, wc = w&1;
  f32x4 acc[4][4] = {};
  int am = t>>1, akq = (t&1)*16;
  int bcl = (t>>4)*2, bn8 = (t&15)*8;

  for (int kk=0; kk<8; kk++){
    int c0 = kk*32;
    {
      const float* s = Av + (size_t)am*256 + c0 + akq;
      float4 v0 = ((const float4*)s)[0];
      float4 v1 = ((const float4*)s)[1];
      float4 v2 = ((const float4*)s)[2];
      float4 v3 = ((const float4*)s)[3];
      short8 h0, h1;
      h0[0]=f2bf(v0.x); h0[1]=f2bf(v0.y); h0[2]=f2bf(v0.z); h0[3]=f2bf(v0.w);
      h0[4]=f2bf(v1.x); h0[5]=f2bf(v1.y); h0[6]=f2bf(v1.z); h0[7]=f2bf(v1.w);
      h1[0]=f2bf(v2.x); h1[1]=f2bf(v2.y); h1[2]=f2bf(v2.z); h1[3]=f2bf(v2.w);
      h1[4]=f2bf(v3.x); h1[5]=f2bf(v3.y); h1[6]=f2bf(v3.z); h1[7]=f2bf(v3.w);
      *(short8*)&At[am][akq]   = h0;
      *(short8*)&At[am][akq+8] = h1;
    }
    {
      const float* s0 = xb + (size_t)(c0+bcl)*PTS + bn8;
      const float* s1 = s0 + PTS;
      float4 a0 = ((const float4*)s0)[0];
      float4 a1 = ((const float4*)s0)[1];
      float4 b0 = ((const float4*)s1)[0];
      float4 b1 = ((const float4*)s1)[1];
      float r0[8] = {a0.x,a0.y,a0.z,a0.w,a1.x,a1.y,a1.z,a1.w};
      float r1[8] = {b0.x,b0.y,b0.z,b0.w,b1.x,b1.y,b1.z,b1.w};
      #pragma unroll
      for (int j=0;j<8;j++){
        unsigned pk = (unsigned)f2bf(r0[j]) | ((unsigned)f2bf(r1[j])<<16);
        *(unsigned*)&Bt[bn8+j][bcl] = pk;
      }
    }
    __syncthreads();
    short8 af[4], bfv[4];
    #pragma unroll
    for (int mi=0;mi<4;mi++) af[mi]  = *(const short8*)&At[64*wr+16*mi+(l&15)][(l>>4)*8];
    #pragma unroll
    for (int ni=0;ni<4;ni++) bfv[ni] = *(const short8*)&Bt[64*wc+16*ni+(l&15)][(l>>4)*8];
    #pragma unroll
    for (int mi=0;mi<4;mi++){
      #pragma unroll
      for (int ni=0;ni<4;ni++)
        acc[mi][ni] = __builtin_amdgcn_mfma_f32_16x16x32_bf16(af[mi], bfv[ni], acc[mi][ni], 0, 0, 0);
    }
    __syncthreads();
  }
  float* ob = outb + (size_t)b*BP;
  #pragma unroll
  for (int mi=0;mi<4;mi++){
    int rbase = mt*128 + 64*wr + 16*mi + ((l>>4)<<2);
    float bvv[4];
    #pragma unroll
    for (int j=0;j<4;j++) bvv[j] = bv[rbase+j];
    #pragma unroll
    for (int ni=0;ni<4;ni++){
      int col = nt*128 + 64*wc + 16*ni + (l&15);
      #pragma unroll
      for (int j=0;j<4;j++)
        ob[(size_t)(rbase+j)*PTS + col] = acc[mi][ni][j] + bvv[j];
    }
  }
}

__global__ void __launch_bounds__(256) k_outgemm(const float* __restrict__ x,
    const float* __restrict__ gma, float* __restrict__ outb){
  __shared__ short Vl[64][264];
  __shared__ short Atl[32][264];
  int t = threadIdx.x;
  int Pq = blockIdx.x, r = blockIdx.y, b = blockIdx.z;
  const float* vsrc = outb + (size_t)b*BP + (size_t)Pq*64*PTS + (size_t)r*256;
  #pragma unroll
  for (int i=0;i<8;i++){
    int row = (t>>5) + 8*i;
    int col = (t&31)*8;
    const float* s = vsrc + (size_t)row*PTS + col;
    float4 v0 = ((const float4*)s)[0];
    float4 v1 = ((const float4*)s)[1];
    short8 h;
    h[0]=f2bf(v0.x); h[1]=f2bf(v0.y); h[2]=f2bf(v0.z); h[3]=f2bf(v0.w);
    h[4]=f2bf(v1.x); h[5]=f2bf(v1.y); h[6]=f2bf(v1.z); h[7]=f2bf(v1.w);
    *(short8*)&Vl[row][col] = h;
  }
  float gm = gma[0];
  const float* attb = outb + ATT_OFF + (size_t)b*65536;
  const float* xb = x + (size_t)b*BP + (size_t)Pq*64*PTS + (size_t)r*256;
  float* ob = outb + (size_t)b*BP + (size_t)Pq*64*PTS + (size_t)r*256;
  int w = t>>6, l = t&63;
  int wr = w>>1, wc = w&1;
  for (int gt=0; gt<8; gt++){
    int g0 = gt*32;
    __syncthreads();
    {
      const float* s = attb + (size_t)t*256 + g0;
      #pragma unroll
      for (int j=0;j<8;j++){
        float4 av = ((const float4*)s)[j];
        Atl[4*j+0][t] = (short)f2bf(av.x);
        Atl[4*j+1][t] = (short)f2bf(av.y);
        Atl[4*j+2][t] = (short)f2bf(av.z);
        Atl[4*j+3][t] = (short)f2bf(av.w);
      }
    }
    __syncthreads();
    f32x4 acc[2] = {};
    #pragma unroll
    for (int ks=0; ks<8; ks++){
      short8 bfrag = *(const short8*)&Atl[16*wc + (l&15)][ks*32 + ((l>>4)<<3)];
      #pragma unroll
      for (int mi=0;mi<2;mi++){
        short8 afrag = *(const short8*)&Vl[32*wr + 16*mi + (l&15)][ks*32 + ((l>>4)<<3)];
        acc[mi] = __builtin_amdgcn_mfma_f32_16x16x32_bf16(afrag, bfrag, acc[mi], 0, 0, 0);
      }
    }
    #pragma unroll
    for (int mi=0;mi<2;mi++){
      int Pl = 32*wr + 16*mi + ((l>>4)<<2);
      int g = g0 + 16*wc + (l&15);
      #pragma unroll
      for (int j=0;j<4;j++){
        size_t a = (size_t)(Pl+j)*PTS + g;
        ob[a] = gm*acc[mi][j] + xb[a];
      }
    }
  }
}

extern "C" void kernel_launch(void* const* d_in, const int* in_sizes, int n_in,
                              void* d_out, int out_size, void* d_ws, size_t ws_size,
                              hipStream_t stream) {
  const float* x   = (const float*)d_in[0];
  const float* Wq  = (const float*)d_in[1];
  const float* bq  = (const float*)d_in[2];
  const float* Wk  = (const float*)d_in[3];
  const float* bk  = (const float*)d_in[4];
  const float* Wv  = (const float*)d_in[5];
  const float* bv  = (const float*)d_in[6];
  const float* Wup = (const float*)d_in[7];
  const float* bup = (const float*)d_in[8];
  const float* gma = (const float*)d_in[9];
  float* out = (float*)d_out;

  bool fast = (d_ws != nullptr) && (ws_size >= WS_NEED);
  unsigned short* vws   = fast ? ((unsigned short*)d_ws) + WS_V_USH   : nullptr;
  unsigned short* attT  = fast ? ((unsigned short*)d_ws) + WS_ATT_USH : nullptr;
  unsigned short* wimg2 = fast ? ((unsigned short*)d_ws) + WS_W_USH   : nullptr;

  if (fast){
    k_wprep2  <<<dim3(36),    256, 0, stream>>>(Wv, Wq, Wk, wimg2);
    k_fused4  <<<dim3(256),   512, 0, stream>>>(x, bv, bq, bk, wimg2, vws, out);
    k_energy2 <<<dim3(64,8),  256, 0, stream>>>(out);
    k_softmax2<<<dim3(8,8),   256, 0, stream>>>(out, Wup, bup, attT);
    k_out5    <<<dim3(128,8), 256, 0, stream>>>(x, gma, vws, attT, out);
  } else {
    k_qk      <<<dim3(128,8),   256, 0, stream>>>(x, Wq, bq, Wk, bk, out);
    k_energy2 <<<dim3(64,8),    256, 0, stream>>>(out);
    k_softmax2<<<dim3(8,8),     256, 0, stream>>>(out, Wup, bup, nullptr);
    k_vgemm   <<<dim3(2,256,8), 256, 0, stream>>>(x, Wv, bv, out);
    k_outgemm <<<dim3(4,128,8), 256, 0, stream>>>(x, gma, out);
  }
}

// Round 18
// 257.529 us; speedup vs baseline: 1.7420x; 1.7420x over previous
//
#include <hip/hip_runtime.h>

#define PTS 32768
#define BP (PTS*256)             // elements per batch of x / v / out
#define QKSZ (16*PTS)
#define Q_OFF ((size_t)0)
#define K_OFF ((size_t)4194304)
#define P_OFF ((size_t)8388608)   // 64 ch * 2048 partials
#define ATT_OFF ((size_t)67108864)
#define WS_V_USH ((size_t)0)
#define WS_ATT_USH ((size_t)67108864)
#define WS_W_USH ((size_t)67633152)   // 9216 x 16B pre-swizzled W image (288 rows x 32 chunks)
#define WS_NEED ((size_t)135450624)

typedef __attribute__((ext_vector_type(8))) short short8;
typedef __attribute__((ext_vector_type(4))) float f32x4;
typedef __attribute__((ext_vector_type(4))) unsigned short ush4;

__device__ __forceinline__ unsigned short f2bf(float f){
  unsigned u = __float_as_uint(f);
  u += 0x7FFFu + ((u>>16)&1u);
  return (unsigned short)(u>>16);
}

__device__ __forceinline__ void bar_lgkm(){
  asm volatile("s_waitcnt lgkmcnt(0)" ::: "memory");
  __builtin_amdgcn_s_barrier();
}

// ---------------- K0: pre-swizzled bf16 W image.
// wimg2[r*256 + q*8 .. +8) = bf16(W[r][ ((q ^ (r&31))*8) .. +8 ])
// rows 0-255 = Wv, 256-271 = Wq, 272-287 = Wk.  9216 16B-chunks total.
__global__ void __launch_bounds__(256) k_wprep2(const float* __restrict__ Wv,
    const float* __restrict__ Wq, const float* __restrict__ Wk,
    unsigned short* __restrict__ wimg2){
  int t = blockIdx.x*256 + threadIdx.x;
  if (t >= 9216) return;
  int r = t>>5, qp = t&31;
  const float* src = (r < 256) ? (Wv + (size_t)r*256)
                    : (r < 272) ? (Wq + (size_t)(r-256)*256)
                                : (Wk + (size_t)(r-272)*256);
  int c0 = (qp ^ (r&31))*8;
  short8 h;
  #pragma unroll
  for (int j=0;j<8;j++) h[j] = (short)f2bf(src[c0+j]);
  *(short8*)&wimg2[(size_t)t*8] = h;
}

// ---------------- FAST K-A: barrier-free fused v/q/k GEMM (round-11/16 verified optimum).
// W fully resident in LDS (144KB, loaded once). Each wave independently computes
// 32p x (256 v-m + 32 qk) tiles: x A-frags direct global->reg (single-depth prefetch;
// depth-2 regressed: VGPR class 64->128 and L3 reuse destroyed, r17), W B-frags from LDS.
// v written [p][f] (flat-identical to k_out5's input layout); q/k transposed via a
// private 1KB LDS slice per wave (no cross-wave sync) -> full-line [f][p] stores.
__global__ void __launch_bounds__(512, 2) k_fused4(const float* __restrict__ x,
    const float* __restrict__ bv, const float* __restrict__ bq, const float* __restrict__ bk,
    const unsigned short* __restrict__ wimg2,
    unsigned short* __restrict__ vws, float* __restrict__ scr){
  __shared__ __align__(16) unsigned short Wl[73728];  // 288 rows x 256 ush, chunk-swizzled (144KB)
  __shared__ __align__(16) float qkT[2048];           // 8 waves x 256 f32 private slices (8KB)
  int t = threadIdx.x;
  int w = t>>6, l = t&63;
  int l15 = l&15, l4 = l>>4;

  { // stage W: linear 16B copy, 18 chunks/thread
    const short8* src = (const short8*)wimg2;
    short8* dst = (short8*)Wl;
    #pragma unroll
    for (int i=0;i<18;i++) dst[t + 512*i] = src[t + 512*i];
  }
  __syncthreads();                 // the ONLY block-wide barrier

  float* qslice = qkT + w*256;
  float bvv[16];
  #pragma unroll
  for (int mb=0;mb<16;mb++) bvv[mb] = bv[mb*16 + l15];
  float bqv = bq[l15], bkv = bk[l15];

  int gw = blockIdx.x*8 + w;       // 0..2047
  for (int it=0; it<4; ++it){
    int tau = gw + 2048*it;        // 0..8191
    int b = tau>>10;
    int p0 = (tau&1023)*32;
    const float* xb = x + (size_t)b*BP + p0 + l15;
    f32x4 acc[2][16] = {};
    f32x4 acce[4] = {};

    // prologue: prefetch kk=0 x values
    float xv[2][8];
    #pragma unroll
    for (int ps=0; ps<2; ps++)
      #pragma unroll
      for (int j=0;j<8;j++)
        xv[ps][j] = xb[(size_t)(l4*8 + j)*PTS + ps*16];

    for (int kk=0; kk<8; kk++){
      short8 af[2];
      #pragma unroll
      for (int ps=0; ps<2; ps++){
        short8 h;
        #pragma unroll
        for (int j=0;j<8;j++) h[j] = (short)f2bf(xv[ps][j]);
        af[ps] = h;
      }
      if (kk < 7){                 // prefetch next kk (stays in flight under MFMA)
        #pragma unroll
        for (int ps=0; ps<2; ps++)
          #pragma unroll
          for (int j=0;j<8;j++)
            xv[ps][j] = xb[(size_t)((kk+1)*32 + l4*8 + j)*PTS + ps*16];
      }
      #pragma unroll
      for (int mb=0; mb<16; mb++){
        int m = mb*16 + l15;
        int phys = (kk*4 + l4) ^ (m&31);
        short8 bf = *(const short8*)&Wl[m*256 + phys*8];
        acc[0][mb] = __builtin_amdgcn_mfma_f32_16x16x32_bf16(af[0], bf, acc[0][mb], 0, 0, 0);
        acc[1][mb] = __builtin_amdgcn_mfma_f32_16x16x32_bf16(af[1], bf, acc[1][mb], 0, 0, 0);
      }
      #pragma unroll
      for (int qs=0; qs<2; qs++){
        int m = 256 + qs*16 + l15;
        int phys = (kk*4 + l4) ^ (m&31);
        short8 bf = *(const short8*)&Wl[m*256 + phys*8];
        acce[qs*2+0] = __builtin_amdgcn_mfma_f32_16x16x32_bf16(af[0], bf, acce[qs*2+0], 0, 0, 0);
        acce[qs*2+1] = __builtin_amdgcn_mfma_f32_16x16x32_bf16(af[1], bf, acce[qs*2+1], 0, 0, 0);
      }
    }

    // v store: vws[b][p][m] (flat == what k_out5 reads). Per instr: 4 p-rows x 32B;
    // adjacent mb instrs complete each 64B sector.
    unsigned short* vb = vws + (size_t)b*BP;
    #pragma unroll
    for (int ps=0; ps<2; ps++){
      #pragma unroll
      for (int j=0;j<4;j++){
        int p = p0 + ps*16 + l4*4 + j;
        unsigned short* row = vb + (size_t)p*256 + l15;
        #pragma unroll
        for (int mb=0; mb<16; mb++)
          row[mb*16] = f2bf(acc[ps][mb][j] + bvv[mb]);
      }
    }
    // q/k: transpose 16p x 16f through private LDS slice, store [f][p] full lines
    #pragma unroll
    for (int ps=0; ps<2; ps++){
      #pragma unroll
      for (int qs=0; qs<2; qs++){
        float bias = qs ? bkv : bqv;
        #pragma unroll
        for (int j=0;j<4;j++){
          int pl = l4*4 + j;
          qslice[pl*16 + (l15 ^ pl)] = acce[qs*2+ps][j] + bias;
        }
        float* qdst = scr + (qs ? K_OFF : Q_OFF) + (size_t)b*QKSZ;
        #pragma unroll
        for (int r=0;r<4;r++){
          int f = r*4 + l4;
          float v = qslice[l15*16 + (f ^ l15)];
          qdst[(size_t)f*PTS + p0 + ps*16 + l15] = v;
        }
      }
    }
  }
}

// ---------------- K2: energy partials, q/k read exactly once.
__global__ void __launch_bounds__(256) k_energy2(float* __restrict__ scr){
  __shared__ float ql[16][512];
  __shared__ float red[256][17];
  int t = threadIdx.x;
  int ch = blockIdx.x, b = blockIdx.y;
  int pbase = ch*512;
  const float* qb = scr + Q_OFF + (size_t)b*QKSZ;
  #pragma unroll
  for (int i=0;i<8;i++){
    int fid = t + 256*i;
    int f = fid>>7, p4 = fid&127;
    float4 v = *(const float4*)(qb + (size_t)f*PTS + pbase + p4*4);
    *(float4*)&ql[f][p4*4] = v;
  }
  __syncthreads();
  const float* kb = scr + K_OFF + (size_t)b*QKSZ + (size_t)ch*8192;
  float acc[16];
  #pragma unroll
  for (int f=0;f<16;f++) acc[f]=0.f;
  for (int i=0;i<32;i++){
    float kv = kb[i*256 + t];
    int p = i*16 + (t>>4);
    #pragma unroll
    for (int f=0;f<16;f++) acc[f] += kv*ql[f][p];
  }
  #pragma unroll
  for (int f=0;f<16;f++) red[t][f] = acc[f];
  __syncthreads();
  int f = t>>4, g = t&15;
  float s = 0.f;
  #pragma unroll
  for (int k=0;k<16;k++) s += red[g + 16*k][f];
  scr[P_OFF + (size_t)ch*2048 + (size_t)b*256 + t] = s;
}

// ---------------- K3: fused reduce + softmax, r-chunked over 64 blocks.
__global__ void __launch_bounds__(256) k_softmax2(float* __restrict__ scr,
    const float* __restrict__ Wup, const float* __restrict__ bup,
    unsigned short* __restrict__ attT){
  __shared__ float el[256];
  int rc = blockIdx.x, b = blockIdx.y, t = threadIdx.x;
  {
    float s = 0.f;
    for (int ch=0; ch<64; ch++) s += scr[P_OFF + (size_t)ch*2048 + (size_t)b*256 + t];
    el[t] = s;
  }
  __syncthreads();
  int ec = t>>4, kw = t&15;
  float bupv = bup[0];
  bool sp = (kw < 3);
  float w0=0.f,w1=0.f,w2=0.f;
  if (sp){ w0 = Wup[kw]; w1 = Wup[3+kw]; w2 = Wup[6+kw]; }
  float m = bupv;
  float sum;
  if (sp){
    #pragma unroll
    for (int rh=0; rh<16; rh++){
      float e = el[rh*16+ec];
      m = fmaxf(m, fmaxf(fmaxf(w0*e, w1*e), w2*e) + bupv);
    }
    sum = 208.f*__expf(bupv - m);
    for (int rh=0; rh<16; rh++){
      float e = el[rh*16+ec];
      sum += __expf(bupv + w0*e - m) + __expf(bupv + w1*e - m) + __expf(bupv + w2*e - m);
    }
  } else {
    sum = 256.f;
  }
  float inv = 1.f/sum;
  float* attp = scr + ATT_OFF + (size_t)b*65536;
  unsigned short* attTp = attT ? (attT + (size_t)b*65536 + (size_t)t*256) : nullptr;
  int r0 = rc*32;
  for (int r=r0; r<r0+32; r++){
    int kh = r&15;
    float v;
    if (sp && kh < 3){
      float e = el[(r>>4)*16 + ec];
      float w = (kh==0)? w0 : ((kh==1)? w1 : w2);
      v = __expf(bupv + w*e - m)*inv;
    } else {
      v = __expf(bupv - m)*inv;
    }
    attp[(size_t)r*256 + t] = v;
    if (attTp) attTp[r] = f2bf(v);
  }
}

// ---------------- FAST K4b: register-resident attT B-frags; V tile prefetched to regs.
__global__ void __launch_bounds__(256, 2) k_out5(const float* __restrict__ x,
    const float* __restrict__ gma,
    const unsigned short* __restrict__ vws,
    const unsigned short* __restrict__ attT,
    float* __restrict__ outb){
  __shared__ __align__(16) unsigned short Vt[32*256];
  __shared__ __align__(16) float Ot[32*260];
  int t = threadIdx.x;
  int b = blockIdx.y;
  int wc = t>>6, l = t&63;
  int l15 = l&15, l4 = l>>4;
  float gm = gma[0];
  const unsigned short* tb = attT + (size_t)b*65536;
  short8 bfv[4][8];
  #pragma unroll
  for (int ni=0;ni<4;ni++){
    int g = wc*64 + ni*16 + l15;
    #pragma unroll
    for (int ks=0;ks<8;ks++)
      bfv[ni][ks] = *(const short8*)(tb + (size_t)g*256 + ks*32 + l4*8);
  }
  short8 vreg[4];
  {
    int p0 = blockIdx.x*32;
    const unsigned short* vsrc = vws + (size_t)b*BP + (size_t)p0*256;
    #pragma unroll
    for (int i=0;i<4;i++) vreg[i] = *(const short8*)(vsrc + (size_t)(i*256+t)*8);
  }
  for (int it=0; it<8; ++it){
    int p0 = (blockIdx.x + 128*it)*32;
    #pragma unroll
    for (int i=0;i<4;i++){
      int idx = i*256 + t;
      int row = idx>>5, chunk = idx&31;
      *(short8*)&Vt[row*256 + ((chunk ^ row)&31)*8] = vreg[i];
    }
    if (it < 7){
      int pn = (blockIdx.x + 128*(it+1))*32;
      const unsigned short* vsrc = vws + (size_t)b*BP + (size_t)pn*256;
      #pragma unroll
      for (int i=0;i<4;i++) vreg[i] = *(const short8*)(vsrc + (size_t)(i*256+t)*8);
    }
    bar_lgkm();
    #pragma unroll
    for (int mi=0;mi<2;mi++){
      int row = mi*16 + l15;
      short8 af[8];
      #pragma unroll
      for (int ks=0;ks<8;ks++){
        int chunk = ks*4 + l4;
        af[ks] = *(const short8*)&Vt[row*256 + ((chunk ^ row)&31)*8];
      }
      #pragma unroll
      for (int ni=0;ni<4;ni++){
        f32x4 acc = {};
        #pragma unroll
        for (int ks=0;ks<8;ks++)
          acc = __builtin_amdgcn_mfma_f32_16x16x32_bf16(af[ks], bfv[ni][ks], acc, 0, 0, 0);
        int gl = wc*64 + ni*16 + l15;
        #pragma unroll
        for (int j=0;j<4;j++)
          Ot[(mi*16 + l4*4 + j)*260 + gl] = acc[j];
      }
    }
    bar_lgkm();
    size_t base = (size_t)b*BP + (size_t)p0*256;
    const float* xb = x + base;
    float* ob = outb + base;
    #pragma unroll
    for (int i=0;i<8;i++){
      int f4 = i*256 + t;
      int row = f4>>6, col = (f4&63)*4;
      float4 a = *(const float4*)&Ot[row*260 + col];
      float4 xv = *(const float4*)(xb + (size_t)f4*4);
      float4 r;
      r.x = gm*a.x + xv.x; r.y = gm*a.y + xv.y;
      r.z = gm*a.z + xv.z; r.w = gm*a.w + xv.w;
      *(float4*)(ob + (size_t)f4*4) = r;
    }
  }
}

// ================= FALLBACK (round-1 pipeline, f32 v in-place in d_out) =================
__global__ void __launch_bounds__(256) k_qk(const float* __restrict__ x,
    const float* __restrict__ Wq, const float* __restrict__ bq,
    const float* __restrict__ Wk, const float* __restrict__ bk,
    float* __restrict__ scr){
  __shared__ float wlds[256][36];
  int t = threadIdx.x;
  int b = blockIdx.y;
  int p = blockIdx.x*256 + t;
  for (int idx = t; idx < 4096; idx += 256){
    int o = idx>>8, c = idx&255;
    wlds[c][o]    = Wq[idx];
    wlds[c][16+o] = Wk[idx];
  }
  __syncthreads();
  const float* xb = x + (size_t)b*BP;
  float qa[16], ka[16];
  #pragma unroll
  for (int o=0;o<16;o++){ qa[o]=0.f; ka[o]=0.f; }
  for (int c=0;c<256;c++){
    float xv = xb[(size_t)c*PTS + p];
    const float4* wrow = (const float4*)(&wlds[c][0]);
    #pragma unroll
    for (int i=0;i<4;i++){
      float4 wq = wrow[i], wk = wrow[4+i];
      qa[4*i+0] += wq.x*xv; qa[4*i+1] += wq.y*xv; qa[4*i+2] += wq.z*xv; qa[4*i+3] += wq.w*xv;
      ka[4*i+0] += wk.x*xv; ka[4*i+1] += wk.y*xv; ka[4*i+2] += wk.z*xv; ka[4*i+3] += wk.w*xv;
    }
  }
  size_t qb = (size_t)b*QKSZ;
  #pragma unroll
  for (int o=0;o<16;o++){
    scr[Q_OFF + qb + (size_t)o*PTS + p] = qa[o] + bq[o];
    scr[K_OFF + qb + (size_t)o*PTS + p] = ka[o] + bk[o];
  }
}

__global__ void __launch_bounds__(256) k_vgemm(const float* __restrict__ x,
    const float* __restrict__ Wv, const float* __restrict__ bv,
    float* __restrict__ outb){
  __shared__ short At[128][40];
  __shared__ short Bt[128][40];
  int t = threadIdx.x;
  int mt = blockIdx.x, nt = blockIdx.y, b = blockIdx.z;
  const float* xb = x + (size_t)b*BP + (size_t)nt*128;
  const float* Av = Wv + (size_t)mt*128*256;
  int w = t>>6, l = t&63;
  int wr = w>>1, wc = w&1;
  f32x4 acc[4][4] = {};
  int am = t>>1, akq = (t&1)*16;
  int bcl = (t>>4)*2, bn8 = (t&15)*8;

  for (int kk=0; kk<8; kk++){
    int c0 = kk*32;
    {
      const float* s = Av + (size_t)am*256 + c0 + akq;
      float4 v0 = ((const float4*)s)[0];
      float4 v1 = ((const float4*)s)[1];
      float4 v2 = ((const float4*)s)[2];
      float4 v3 = ((const float4*)s)[3];
      short8 h0, h1;
      h0[0]=f2bf(v0.x); h0[1]=f2bf(v0.y); h0[2]=f2bf(v0.z); h0[3]=f2bf(v0.w);
      h0[4]=f2bf(v1.x); h0[5]=f2bf(v1.y); h0[6]=f2bf(v1.z); h0[7]=f2bf(v1.w);
      h1[0]=f2bf(v2.x); h1[1]=f2bf(v2.y); h1[2]=f2bf(v2.z); h1[3]=f2bf(v2.w);
      h1[4]=f2bf(v3.x); h1[5]=f2bf(v3.y); h1[6]=f2bf(v3.z); h1[7]=f2bf(v3.w);
      *(short8*)&At[am][akq]   = h0;
      *(short8*)&At[am][akq+8] = h1;
    }
    {
      const float* s0 = xb + (size_t)(c0+bcl)*PTS + bn8;
      const float* s1 = s0 + PTS;
      float4 a0 = ((const float4*)s0)[0];
      float4 a1 = ((const float4*)s0)[1];
      float4 b0 = ((const float4*)s1)[0];
      float4 b1 = ((const float4*)s1)[1];
      float r0[8] = {a0.x,a0.y,a0.z,a0.w,a1.x,a1.y,a1.z,a1.w};
      float r1[8] = {b0.x,b0.y,b0.z,b0.w,b1.x,b1.y,b1.z,b1.w};
      #pragma unroll
      for (int j=0;j<8;j++){
        unsigned pk = (unsigned)f2bf(r0[j]) | ((unsigned)f2bf(r1[j])<<16);
        *(unsigned*)&Bt[bn8+j][bcl] = pk;
      }
    }
    __syncthreads();
    short8 af[4], bfv[4];
    #pragma unroll
    for (int mi=0;mi<4;mi++) af[mi]  = *(const short8*)&At[64*wr+16*mi+(l&15)][(l>>4)*8];
    #pragma unroll
    for (int ni=0;ni<4;ni++) bfv[ni] = *(const short8*)&Bt[64*wc+16*ni+(l&15)][(l>>4)*8];
    #pragma unroll
    for (int mi=0;mi<4;mi++){
      #pragma unroll
      for (int ni=0;ni<4;ni++)
        acc[mi][ni] = __builtin_amdgcn_mfma_f32_16x16x32_bf16(af[mi], bfv[ni], acc[mi][ni], 0, 0, 0);
    }
    __syncthreads();
  }
  float* ob = outb + (size_t)b*BP;
  #pragma unroll
  for (int mi=0;mi<4;mi++){
    int rbase = mt*128 + 64*wr + 16*mi + ((l>>4)<<2);
    float bvv[4];
    #pragma unroll
    for (int j=0;j<4;j++) bvv[j] = bv[rbase+j];
    #pragma unroll
    for (int ni=0;ni<4;ni++){
      int col = nt*128 + 64*wc + 16*ni + (l&15);
      #pragma unroll
      for (int j=0;j<4;j++)
        ob[(size_t)(rbase+j)*PTS + col] = acc[mi][ni][j] + bvv[j];
    }
  }
}

__global__ void __launch_bounds__(256) k_outgemm(const float* __restrict__ x,
    const float* __restrict__ gma, float* __restrict__ outb){
  __shared__ short Vl[64][264];
  __shared__ short Atl[32][264];
  int t = threadIdx.x;
  int Pq = blockIdx.x, r = blockIdx.y, b = blockIdx.z;
  const float* vsrc = outb + (size_t)b*BP + (size_t)Pq*64*PTS + (size_t)r*256;
  #pragma unroll
  for (int i=0;i<8;i++){
    int row = (t>>5) + 8*i;
    int col = (t&31)*8;
    const float* s = vsrc + (size_t)row*PTS + col;
    float4 v0 = ((const float4*)s)[0];
    float4 v1 = ((const float4*)s)[1];
    short8 h;
    h[0]=f2bf(v0.x); h[1]=f2bf(v0.y); h[2]=f2bf(v0.z); h[3]=f2bf(v0.w);
    h[4]=f2bf(v1.x); h[5]=f2bf(v1.y); h[6]=f2bf(v1.z); h[7]=f2bf(v1.w);
    *(short8*)&Vl[row][col] = h;
  }
  float gm = gma[0];
  const float* attb = outb + ATT_OFF + (size_t)b*65536;
  const float* xb = x + (size_t)b*BP + (size_t)Pq*64*PTS + (size_t)r*256;
  float* ob = outb + (size_t)b*BP + (size_t)Pq*64*PTS + (size_t)r*256;
  int w = t>>6, l = t&63;
  int wr = w>>1, wc = w&1;
  for (int gt=0; gt<8; gt++){
    int g0 = gt*32;
    __syncthreads();
    {
      const float* s = attb + (size_t)t*256 + g0;
      #pragma unroll
      for (int j=0;j<8;j++){
        float4 av = ((const float4*)s)[j];
        Atl[4*j+0][t] = (short)f2bf(av.x);
        Atl[4*j+1][t] = (short)f2bf(av.y);
        Atl[4*j+2][t] = (short)f2bf(av.z);
        Atl[4*j+3][t] = (short)f2bf(av.w);
      }
    }
    __syncthreads();
    f32x4 acc[2] = {};
    #pragma unroll
    for (int ks=0; ks<8; ks++){
      short8 bfrag = *(const short8*)&Atl[16*wc + (l&15)][ks*32 + ((l>>4)<<3)];
      #pragma unroll
      for (int mi=0;mi<2;mi++){
        short8 afrag = *(const short8*)&Vl[32*wr + 16*mi + (l&15)][ks*32 + ((l>>4)<<3)];
        acc[mi] = __builtin_amdgcn_mfma_f32_16x16x32_bf16(afrag, bfrag, acc[mi], 0, 0, 0);
      }
    }
    #pragma unroll
    for (int mi=0;mi<2;mi++){
      int Pl = 32*wr + 16*mi + ((l>>4)<<2);
      int g = g0 + 16*wc + (l&15);
      #pragma unroll
      for (int j=0;j<4;j++){
        size_t a = (size_t)(Pl+j)*PTS + g;
        ob[a] = gm*acc[mi][j] + xb[a];
      }
    }
  }
}

extern "C" void kernel_launch(void* const* d_in, const int* in_sizes, int n_in,
                              void* d_out, int out_size, void* d_ws, size_t ws_size,
                              hipStream_t stream) {
  const float* x   = (const float*)d_in[0];
  const float* Wq  = (const float*)d_in[1];
  const float* bq  = (const float*)d_in[2];
  const float* Wk  = (const float*)d_in[3];
  const float* bk  = (const float*)d_in[4];
  const float* Wv  = (const float*)d_in[5];
  const float* bv  = (const float*)d_in[6];
  const float* Wup = (const float*)d_in[7];
  const float* bup = (const float*)d_in[8];
  const float* gma = (const float*)d_in[9];
  float* out = (float*)d_out;

  bool fast = (d_ws != nullptr) && (ws_size >= WS_NEED);
  unsigned short* vws   = fast ? ((unsigned short*)d_ws) + WS_V_USH   : nullptr;
  unsigned short* attT  = fast ? ((unsigned short*)d_ws) + WS_ATT_USH : nullptr;
  unsigned short* wimg2 = fast ? ((unsigned short*)d_ws) + WS_W_USH   : nullptr;

  if (fast){
    k_wprep2  <<<dim3(36),    256, 0, stream>>>(Wv, Wq, Wk, wimg2);
    k_fused4  <<<dim3(256),   512, 0, stream>>>(x, bv, bq, bk, wimg2, vws, out);
    k_energy2 <<<dim3(64,8),  256, 0, stream>>>(out);
    k_softmax2<<<dim3(8,8),   256, 0, stream>>>(out, Wup, bup, attT);
    k_out5    <<<dim3(128,8), 256, 0, stream>>>(x, gma, vws, attT, out);
  } else {
    k_qk      <<<dim3(128,8),   256, 0, stream>>>(x, Wq, bq, Wk, bk, out);
    k_energy2 <<<dim3(64,8),    256, 0, stream>>>(out);
    k_softmax2<<<dim3(8,8),     256, 0, stream>>>(out, Wup, bup, nullptr);
    k_vgemm   <<<dim3(2,256,8), 256, 0, stream>>>(x, Wv, bv, out);
    k_outgemm <<<dim3(4,128,8), 256, 0, stream>>>(x, gma, out);
  }
}